// Round 3
// baseline (10.629 us; speedup 1.0000x reference)
//
#include <hip/hip_runtime.h>

// Problem constants (from reference):
//   R=4, B=2048, S=10, U=20000, D=128
// Output: [R*B, D] fp32 = mean over the SET (dedup'd) of sampled neighbor embeddings.

#define RR 4
#define BB 2048
#define SS 10
#define UU 20000
#define DD 128
#define ROWS (RR * BB)          // 8192
#define NCHUNK 8                // column chunks of 16 floats, pinned to XCDs
#define RPT 2                   // rows per thread (ILP: 20 gathers in flight)

typedef float vfloat4 __attribute__((ext_vector_type(4)));

// Grid: blockIdx & 7 = column chunk (16 floats) -> round-robin XCD dispatch
// keeps each XCD's gathers inside a 20000 x 64 B = 1.28 MB L2-resident slice.
// Block: 256 threads = 64 row-slots x 4 float4-lanes; each thread does 2 rows.
__global__ __launch_bounds__(256) void mean_agg_kernel(
    const int* __restrict__ neigh_idx,   // [ROWS, S]
    const float* __restrict__ embed,     // [U, D]
    float* __restrict__ out)             // [ROWS, D]
{
    const int chunk  = blockIdx.x & (NCHUNK - 1);
    const int group  = blockIdx.x >> 3;           // row group of 128
    const int tid    = threadIdx.x;
    const int slot   = tid >> 2;                  // 0..63
    const int c4l    = tid & 3;                   // 0..3
    const int col4   = chunk * 4 + c4l;           // float4 index within row

    const vfloat4* __restrict__ esrc =
        reinterpret_cast<const vfloat4*>(embed) + col4;

    // ---- load indices for both rows, vectorized as int2 (8B-aligned) ----
    int id[RPT][SS];
    #pragma unroll
    for (int rr = 0; rr < RPT; ++rr) {
        const int row = group * 128 + rr * 64 + slot;
        const int2* ip2 = reinterpret_cast<const int2*>(neigh_idx + row * SS);
        #pragma unroll
        for (int j = 0; j < SS / 2; ++j) {
            const int2 p = ip2[j];
            id[rr][2 * j]     = p.x;
            id[rr][2 * j + 1] = p.y;
        }
    }

    // ---- issue all gathers (dup gathers are harmless; dedup gates the add) --
    vfloat4 acc[RPT];
    int cnt[RPT];
    #pragma unroll
    for (int rr = 0; rr < RPT; ++rr) {
        acc[rr] = (vfloat4){0.f, 0.f, 0.f, 0.f};
        cnt[rr] = 0;
        #pragma unroll
        for (int j = 0; j < SS; ++j) {
            bool dup = false;
            #pragma unroll
            for (int i = 0; i < j; ++i) dup = dup || (id[rr][i] == id[rr][j]);
            if (!dup) {
                ++cnt[rr];
                acc[rr] += esrc[(size_t)id[rr][j] * (DD / 4)];
            }
        }
    }

    // ---- scale + nontemporal store (don't evict embed slice from L2) ----
    #pragma unroll
    for (int rr = 0; rr < RPT; ++rr) {
        const int row = group * 128 + rr * 64 + slot;
        acc[rr] *= (1.0f / (float)cnt[rr]);
        __builtin_nontemporal_store(
            acc[rr], reinterpret_cast<vfloat4*>(out) + (size_t)row * 32 + col4);
    }
}

extern "C" void kernel_launch(void* const* d_in, const int* in_sizes, int n_in,
                              void* d_out, int out_size, void* d_ws, size_t ws_size,
                              hipStream_t stream) {
    const int*   neigh_idx = (const int*)d_in[0];    // [R,B,S] int32
    const float* embed     = (const float*)d_in[1];  // [U,D] fp32
    float*       out       = (float*)d_out;          // [ROWS, D] fp32

    const int block = 256;
    const int grid  = (ROWS / 128) * NCHUNK;         // 64 * 8 = 512 blocks

    mean_agg_kernel<<<grid, block, 0, stream>>>(neigh_idx, embed, out);
}